// Round 6
// baseline (97.399 us; speedup 1.0000x reference)
//
#include <hip/hip_runtime.h>

typedef __attribute__((ext_vector_type(8))) short short8v;
typedef __attribute__((ext_vector_type(4))) float float4v;
typedef unsigned int uint;

#define TWO_LOG2E 2.8853900817779268f   // 2*log2(e)
#define LOG2E     1.4426950408889634f

// ---------------------------------------------------------------------------
// f32 -> bf16 helpers (RNE), packing pairs into uint words
// ---------------------------------------------------------------------------
__device__ inline uint rne_bf16(float x) {
    uint u = __float_as_uint(x);
    return (u + 0x7fffu + ((u >> 16) & 1u)) >> 16;
}
__device__ inline uint pack_hi_lo(float a0, float a1, uint& lo_pack) {
    const uint h0 = rne_bf16(a0), h1 = rne_bf16(a1);
    const float f0 = __uint_as_float(h0 << 16), f1 = __uint_as_float(h1 << 16);
    const float l0 = a0 - f0, l1 = a1 - f1;
    lo_pack = (rne_bf16(l1) << 16) | rne_bf16(l0);
    return (h1 << 16) | h0;
}

// ---------------------------------------------------------------------------
// prep_a: split A = [query(1024 rows); key(4096 rows)] x 512 into bf16 hi/lo.
// ---------------------------------------------------------------------------
__global__ __launch_bounds__(256) void prep_a(
    const float* __restrict__ query, const float* __restrict__ key,
    const int* __restrict__ vlen,
    ushort* __restrict__ A_hi, ushort* __restrict__ A_lo)
{
    const int t = blockIdx.x * 256 + threadIdx.x;   // 327680 total
    const int row = t >> 6;
    const int cg = (t & 63) * 8;
    if (row >= 1024) {
        const int kr = (row - 1024) & 1023, b = (row - 1024) >> 10;
        if ((kr & ~63) >= vlen[b]) return;
    }
    const float* src = (row < 1024) ? (query + (size_t)row * 512 + cg)
                                    : (key + (size_t)(row - 1024) * 512 + cg);
    const float4 x0 = *(const float4*)src;
    const float4 x1 = *(const float4*)(src + 4);
    uint h0, h1, h2, h3, l0, l1, l2, l3;
    h0 = pack_hi_lo(x0.x, x0.y, l0);
    h1 = pack_hi_lo(x0.z, x0.w, l1);
    h2 = pack_hi_lo(x1.x, x1.y, l2);
    h3 = pack_hi_lo(x1.z, x1.w, l3);
    *(uint4*)(A_hi + (size_t)row * 512 + cg) = make_uint4(h0, h1, h2, h3);
    *(uint4*)(A_lo + (size_t)row * 512 + cg) = make_uint4(l0, l1, l2, l3);
}

// ---------------------------------------------------------------------------
// prep_w: WT_hi/lo[w][n][k] = split(W_w[k][n]) — transpose + hi/lo split.
// ---------------------------------------------------------------------------
__global__ __launch_bounds__(256) void prep_w(
    const float* __restrict__ Wq, const float* __restrict__ Wk,
    ushort* __restrict__ WT_hi, ushort* __restrict__ WT_lo)
{
    const int t = blockIdx.x * 256 + threadIdx.x;   // 32768 total
    const int n = t & 255;
    const int kg = ((t >> 8) & 63) * 8;
    const int w = t >> 14;
    const float* W = w ? Wk : Wq;
    float x[8];
    #pragma unroll
    for (int i = 0; i < 8; ++i) x[i] = W[(size_t)(kg + i) * 256 + n];
    uint h0, h1, h2, h3, l0, l1, l2, l3;
    h0 = pack_hi_lo(x[0], x[1], l0);
    h1 = pack_hi_lo(x[2], x[3], l1);
    h2 = pack_hi_lo(x[4], x[5], l2);
    h3 = pack_hi_lo(x[6], x[7], l3);
    const size_t off = ((size_t)w * 256 + n) * 512 + kg;
    *(uint4*)(WT_hi + off) = make_uint4(h0, h1, h2, h3);
    *(uint4*)(WT_lo + off) = make_uint4(l0, l1, l2, l3);
}

// ---------------------------------------------------------------------------
// Kernel P (MFMA): proj via 3-MFMA hi/lo bf16 split. Wave tile 32m x 64n
// (640 waves -> 2x the SIMD coverage of the 64x64 version), K=512 by 32.
// ---------------------------------------------------------------------------
#define LOADF(s, kbase) { const int ko = (kbase) + half * 8;                \
    _Pragma("unroll") for (int f = 0; f < 2; ++f) {                         \
        ah##s[f] = *(const short8v*)(a_h + (size_t)(f * 16) * 512 + ko);    \
        al##s[f] = *(const short8v*)(a_l + (size_t)(f * 16) * 512 + ko); }  \
    _Pragma("unroll") for (int f = 0; f < 4; ++f) {                         \
        bh##s[f] = *(const short8v*)(wt_h + (size_t)(f * 16) * 512 + ko);   \
        bl##s[f] = *(const short8v*)(wt_l + (size_t)(f * 16) * 512 + ko); } }

#define MFMAS(s)                                                                          \
    _Pragma("unroll") for (int mf = 0; mf < 2; ++mf)                                      \
    _Pragma("unroll") for (int nf = 0; nf < 4; ++nf) {                                    \
        acc[mf][nf] = __builtin_amdgcn_mfma_f32_16x16x32_bf16(ah##s[mf], bh##s[nf], acc[mf][nf], 0, 0, 0); \
        acc[mf][nf] = __builtin_amdgcn_mfma_f32_16x16x32_bf16(ah##s[mf], bl##s[nf], acc[mf][nf], 0, 0, 0); \
        acc[mf][nf] = __builtin_amdgcn_mfma_f32_16x16x32_bf16(al##s[mf], bh##s[nf], acc[mf][nf], 0, 0, 0); }

__global__ __launch_bounds__(64) void proj_mfma(
    const ushort* __restrict__ A_hi, const ushort* __restrict__ A_lo,
    const ushort* __restrict__ WT_hi, const ushort* __restrict__ WT_lo,
    const int* __restrict__ valid_len,
    float* __restrict__ EqT, float* __restrict__ EkT)
{
    const int lane = threadIdx.x;
    const int n0 = blockIdx.x * 64;
    const int m0 = blockIdx.y * 32;
    const bool isq = (m0 < 1024);
    int b = 0, kk0 = 0;
    if (!isq) {
        kk0 = (m0 - 1024) & 1023;
        b = (m0 - 1024) >> 10;
        if (kk0 >= valid_len[b]) return;
    }
    const int r = lane & 15, half = lane >> 4;
    const size_t wsel = isq ? 0 : (size_t)256 * 512;
    const ushort* wt_h = WT_hi + wsel + (size_t)(n0 + r) * 512;
    const ushort* wt_l = WT_lo + wsel + (size_t)(n0 + r) * 512;
    const ushort* a_h = A_hi + (size_t)(m0 + r) * 512;
    const ushort* a_l = A_lo + (size_t)(m0 + r) * 512;

    float4v acc[2][4] = {{{0.f}}};
    short8v ah0[2], al0[2], bh0[4], bl0[4];
    short8v ah1[2], al1[2], bh1[4], bl1[4];

    LOADF(0, 0);
    for (int kt = 0; kt < 512; kt += 64) {
        LOADF(1, kt + 32);
        MFMAS(0);
        if (kt + 64 < 512) LOADF(0, kt + 64);
        MFMAS(1);
    }

    #pragma unroll
    for (int mf = 0; mf < 2; ++mf) {
        #pragma unroll
        for (int nf = 0; nf < 4; ++nf) {
            float4v e;
            #pragma unroll
            for (int i = 0; i < 4; ++i)
                e[i] = __builtin_amdgcn_exp2f(acc[mf][nf][i] * TWO_LOG2E);
            if (isq) {
                *(float4v*)(EqT + (size_t)(n0 + nf * 16 + r) * 1024 +
                            m0 + mf * 16 + half * 4) = e;
            } else {
                *(float4v*)(EkT + (size_t)(b * 256 + n0 + nf * 16 + r) * 1024 +
                            kk0 + mf * 16 + half * 4) = e;
            }
        }
    }
}

// ---------------------------------------------------------------------------
// Score pass A: partial half-scores.
// Block = (b, 16q, k-quarter, h-half): 512 blocks x 256 thr (2048 waves).
// P_hh[b*256+q][k] = sum_{h in half} wv[h]*(1 - 2*rcp(Eq*Ek+1)) accumulated
// as cw_half - 2*acc. Full score = P0 + P1. XCD-chunked swizzle keeps the
// 16 q-blocks sharing one EkT slab on one XCD's L2.
// ---------------------------------------------------------------------------
__global__ __launch_bounds__(256) void score_partial(
    const float* __restrict__ EqT, const float* __restrict__ EkT,
    const float* __restrict__ wv, const int* __restrict__ valid_len,
    float* __restrict__ P0, float* __restrict__ P1)
{
    __shared__ float wv_s[128];
    __shared__ float eqs[128][16];

    const int orig = blockIdx.x;                 // 512 blocks
    const int wg = (orig & 7) * 64 + (orig >> 3);
    const int qg = wg & 15;
    const int kq = (wg >> 4) & 3;
    const int hh = (wg >> 6) & 1;
    const int b  = wg >> 7;

    const int tid = threadIdx.x;
    const int vlen = valid_len[b];
    if (kq * 256 >= vlen) return;                // block-uniform skip
    const int k = kq * 256 + tid;
    const int q0 = qg * 16;

    if (tid < 128) {
        wv_s[tid] = wv[hh * 128 + tid];
        const float* ep = EqT + (size_t)(hh * 128 + tid) * 1024 + b * 256 + q0;
        #pragma unroll
        for (int j = 0; j < 4; ++j)
            *(float4*)&eqs[tid][j * 4] = *(const float4*)(ep + j * 4);
    }
    __syncthreads();

    float acc[16] = {};
    float cw = 0.f;
    const bool v = (k < vlen);

    if (v) {
        const float* ekp = EkT + ((size_t)(b * 256 + hh * 128)) * 1024 + k;
        #pragma unroll 2
        for (int h = 0; h < 128; ++h) {
            const float ek = ekp[(size_t)h * 1024];
            const float w = wv_s[h];
            cw += w;
            #pragma unroll
            for (int j = 0; j < 4; ++j) {
                const float4 eq = *(const float4*)&eqs[h][j * 4];
                acc[j*4+0] = fmaf(w, __builtin_amdgcn_rcpf(fmaf(eq.x, ek, 1.f)), acc[j*4+0]);
                acc[j*4+1] = fmaf(w, __builtin_amdgcn_rcpf(fmaf(eq.y, ek, 1.f)), acc[j*4+1]);
                acc[j*4+2] = fmaf(w, __builtin_amdgcn_rcpf(fmaf(eq.z, ek, 1.f)), acc[j*4+2]);
                acc[j*4+3] = fmaf(w, __builtin_amdgcn_rcpf(fmaf(eq.w, ek, 1.f)), acc[j*4+3]);
            }
        }
    }

    float* __restrict__ P = hh ? P1 : P0;
    #pragma unroll
    for (int qi = 0; qi < 16; ++qi)
        P[(size_t)(b * 256 + q0 + qi) * 1024 + k] = fmaf(-2.f, acc[qi], cw);
}

// ---------------------------------------------------------------------------
// Score pass B: masked softmax over s = P0 + P1; writes attn in-place to P0.
// Block = (b, 4q); 1024 threads; thread owns k = tid.
// ---------------------------------------------------------------------------
__global__ __launch_bounds__(1024) void softmax_kernel(
    const float* __restrict__ P1, const int* __restrict__ valid_len,
    float* __restrict__ attn /* == P0 */)
{
    __shared__ float red[16][4];

    const int tid = threadIdx.x;
    const int b = blockIdx.x >> 6;
    const int q0 = (blockIdx.x & 63) << 2;

    const int vlen = valid_len[b];
    const int k = tid;
    const bool v = (k < vlen);

    float s[4], m[4];
    #pragma unroll
    for (int q = 0; q < 4; ++q) {
        const size_t off = (size_t)(b * 256 + q0 + q) * 1024 + k;
        s[q] = attn[off] + P1[off];
        m[q] = v ? s[q] : -1e30f;
    }
    #pragma unroll
    for (int o = 32; o; o >>= 1) {
        #pragma unroll
        for (int q = 0; q < 4; ++q) m[q] = fmaxf(m[q], __shfl_xor(m[q], o));
    }
    const int wid = tid >> 6;
    if ((tid & 63) == 0) {
        #pragma unroll
        for (int q = 0; q < 4; ++q) red[wid][q] = m[q];
    }
    __syncthreads();
    #pragma unroll
    for (int q = 0; q < 4; ++q) {
        float mm = red[0][q];
        #pragma unroll
        for (int w = 1; w < 16; ++w) mm = fmaxf(mm, red[w][q]);
        m[q] = mm;
    }
    __syncthreads();

    float p[4], l[4];
    #pragma unroll
    for (int q = 0; q < 4; ++q) {
        p[q] = v ? __builtin_amdgcn_exp2f((s[q] - m[q]) * LOG2E) : 0.f;
        l[q] = p[q];
    }
    #pragma unroll
    for (int o = 32; o; o >>= 1) {
        #pragma unroll
        for (int q = 0; q < 4; ++q) l[q] += __shfl_xor(l[q], o);
    }
    if ((tid & 63) == 0) {
        #pragma unroll
        for (int q = 0; q < 4; ++q) red[wid][q] = l[q];
    }
    __syncthreads();
    #pragma unroll
    for (int q = 0; q < 4; ++q) {
        float ss = red[0][q];
        #pragma unroll
        for (int w = 1; w < 16; ++w) ss += red[w][q];
        const float rl = __builtin_amdgcn_rcpf(ss);
        attn[(size_t)(b * 256 + q0 + q) * 1024 + k] = p[q] * rl;
    }
}

// ---------------------------------------------------------------------------
// Kernel D: out[b] = attn[b] @ value[b]   (f32 GEMM, 32x64 tile, BK=32)
// ---------------------------------------------------------------------------
__global__ __launch_bounds__(256) void pv_kernel(
    const float* __restrict__ attn, const float* __restrict__ value,
    const int* __restrict__ valid_len,
    float* __restrict__ out)
{
    __shared__ float As[32][34];
    __shared__ float Bs[32][64];

    const int tid = threadIdx.x;
    const int b = blockIdx.z;
    const int m0 = blockIdx.y * 32, n0 = blockIdx.x * 64;
    const float* A = attn + ((size_t)b * 256 + m0) * 1024;
    const float* B = value + (size_t)b * 1024 * 512;

    const int kend = (valid_len[b] + 31) & ~31;

    const int tx = tid & 15, ty = tid >> 4;
    const int lr = tid >> 3, lc = (tid & 7) * 4;
    const int br = tid >> 4, bc = (tid & 15) * 4;

    float4 av  = *(const float4*)(A + (size_t)lr * 1024 + lc);
    float4 bv0 = *(const float4*)(B + (size_t)br * 512 + n0 + bc);
    float4 bv1 = *(const float4*)(B + (size_t)(br + 16) * 512 + n0 + bc);

    float c[2][4] = {};

    for (int kt = 0; kt < kend; kt += 32) {
        __syncthreads();
        As[lc + 0][lr] = av.x; As[lc + 1][lr] = av.y;
        As[lc + 2][lr] = av.z; As[lc + 3][lr] = av.w;
        *(float4*)&Bs[br][bc] = bv0;
        *(float4*)&Bs[br + 16][bc] = bv1;
        __syncthreads();
        if (kt + 32 < kend) {
            av  = *(const float4*)(A + (size_t)lr * 1024 + kt + 32 + lc);
            bv0 = *(const float4*)(B + (size_t)(kt + 32 + br) * 512 + n0 + bc);
            bv1 = *(const float4*)(B + (size_t)(kt + 48 + br) * 512 + n0 + bc);
        }
        #pragma unroll
        for (int k = 0; k < 32; ++k) {
            const float2 a = *(const float2*)&As[k][ty * 2];
            const float4 bb = *(const float4*)&Bs[k][tx * 4];
            c[0][0] = fmaf(a.x, bb.x, c[0][0]);
            c[0][1] = fmaf(a.x, bb.y, c[0][1]);
            c[0][2] = fmaf(a.x, bb.z, c[0][2]);
            c[0][3] = fmaf(a.x, bb.w, c[0][3]);
            c[1][0] = fmaf(a.y, bb.x, c[1][0]);
            c[1][1] = fmaf(a.y, bb.y, c[1][1]);
            c[1][2] = fmaf(a.y, bb.z, c[1][2]);
            c[1][3] = fmaf(a.y, bb.w, c[1][3]);
        }
    }

    #pragma unroll
    for (int i = 0; i < 2; ++i) {
        float4 o;
        o.x = c[i][0]; o.y = c[i][1]; o.z = c[i][2]; o.w = c[i][3];
        *(float4*)(out + (size_t)b * 256 * 512 +
                   (size_t)(m0 + ty * 2 + i) * 512 + n0 + tx * 4) = o;
    }
}

// ---------------------------------------------------------------------------
extern "C" void kernel_launch(void* const* d_in, const int* in_sizes, int n_in,
                              void* d_out, int out_size, void* d_ws, size_t ws_size,
                              hipStream_t stream)
{
    const float* query = (const float*)d_in[0];   // [4,256,512]
    const float* key   = (const float*)d_in[1];   // [4,1024,512]
    const float* value = (const float*)d_in[2];   // [4,1024,512]
    const int*   vlen  = (const int*)d_in[3];     // [4]
    const float* Wq    = (const float*)d_in[4];   // [512,256]
    const float* Wk    = (const float*)d_in[5];   // [512,256]
    const float* wv    = (const float*)d_in[6];   // [256]
    float* out = (float*)d_out;                   // [4,256,512]

    float*  EqT   = (float*)d_ws;                 // [256][1024]   = 262144 f
    float*  EkT   = EqT + 262144;                 // [4][256][1024]= 1048576 f
    float*  P0    = EkT + 1048576;                // [1024][1024]  = 1048576 f (also attn)
    float*  P1    = P0 + 1048576;                 // [1024][1024]  = 1048576 f
    ushort* A_hi  = (ushort*)(P1 + 1048576);      // [5120][512]   = 2621440 s
    ushort* A_lo  = A_hi + 2621440;
    ushort* WT_hi = A_lo + 2621440;               // [2][256][512] = 262144 s
    ushort* WT_lo = WT_hi + 262144;

    hipLaunchKernelGGL(prep_w, dim3(128), dim3(256), 0, stream,
                       Wq, Wk, WT_hi, WT_lo);
    hipLaunchKernelGGL(prep_a, dim3(1280), dim3(256), 0, stream,
                       query, key, vlen, A_hi, A_lo);
    hipLaunchKernelGGL(proj_mfma, dim3(4, 160), dim3(64), 0, stream,
                       A_hi, A_lo, WT_hi, WT_lo, vlen, EqT, EkT);
    hipLaunchKernelGGL(score_partial, dim3(512), dim3(256), 0, stream,
                       EqT, EkT, wv, vlen, P0, P1);
    hipLaunchKernelGGL(softmax_kernel, dim3(256), dim3(1024), 0, stream,
                       P1, vlen, P0);
    hipLaunchKernelGGL(pv_kernel, dim3(8, 8, 4), dim3(256), 0, stream,
                       P0, value, vlen, out);
}

// Round 7
// 87.026 us; speedup vs baseline: 1.1192x; 1.1192x over previous
//
#include <hip/hip_runtime.h>

typedef __attribute__((ext_vector_type(8))) short short8v;
typedef __attribute__((ext_vector_type(4))) float float4v;
typedef unsigned int uint;

#define TWO_LOG2E 2.8853900817779268f   // 2*log2(e)
#define LOG2E     1.4426950408889634f

// ---------------------------------------------------------------------------
// f32 -> bf16 helpers (RNE), packing pairs into uint words
// ---------------------------------------------------------------------------
__device__ inline uint rne_bf16(float x) {
    uint u = __float_as_uint(x);
    return (u + 0x7fffu + ((u >> 16) & 1u)) >> 16;
}
__device__ inline uint pack_hi_lo(float a0, float a1, uint& lo_pack) {
    const uint h0 = rne_bf16(a0), h1 = rne_bf16(a1);
    const float f0 = __uint_as_float(h0 << 16), f1 = __uint_as_float(h1 << 16);
    const float l0 = a0 - f0, l1 = a1 - f1;
    lo_pack = (rne_bf16(l1) << 16) | rne_bf16(l0);
    return (h1 << 16) | h0;
}

// ---------------------------------------------------------------------------
// prep_a: split A = [query(1024 rows); key(4096 rows)] x 512 into bf16 hi/lo.
// ---------------------------------------------------------------------------
__global__ __launch_bounds__(256) void prep_a(
    const float* __restrict__ query, const float* __restrict__ key,
    const int* __restrict__ vlen,
    ushort* __restrict__ A_hi, ushort* __restrict__ A_lo)
{
    const int t = blockIdx.x * 256 + threadIdx.x;   // 327680 total
    const int row = t >> 6;
    const int cg = (t & 63) * 8;
    if (row >= 1024) {
        const int kr = (row - 1024) & 1023, b = (row - 1024) >> 10;
        if ((kr & ~63) >= vlen[b]) return;
    }
    const float* src = (row < 1024) ? (query + (size_t)row * 512 + cg)
                                    : (key + (size_t)(row - 1024) * 512 + cg);
    const float4 x0 = *(const float4*)src;
    const float4 x1 = *(const float4*)(src + 4);
    uint h0, h1, h2, h3, l0, l1, l2, l3;
    h0 = pack_hi_lo(x0.x, x0.y, l0);
    h1 = pack_hi_lo(x0.z, x0.w, l1);
    h2 = pack_hi_lo(x1.x, x1.y, l2);
    h3 = pack_hi_lo(x1.z, x1.w, l3);
    *(uint4*)(A_hi + (size_t)row * 512 + cg) = make_uint4(h0, h1, h2, h3);
    *(uint4*)(A_lo + (size_t)row * 512 + cg) = make_uint4(l0, l1, l2, l3);
}

// ---------------------------------------------------------------------------
// prep_w: WT_hi/lo[w][n][k] = split(W_w[k][n]) — transpose + hi/lo split.
// ---------------------------------------------------------------------------
__global__ __launch_bounds__(256) void prep_w(
    const float* __restrict__ Wq, const float* __restrict__ Wk,
    ushort* __restrict__ WT_hi, ushort* __restrict__ WT_lo)
{
    const int t = blockIdx.x * 256 + threadIdx.x;   // 32768 total
    const int n = t & 255;
    const int kg = ((t >> 8) & 63) * 8;
    const int w = t >> 14;
    const float* W = w ? Wk : Wq;
    float x[8];
    #pragma unroll
    for (int i = 0; i < 8; ++i) x[i] = W[(size_t)(kg + i) * 256 + n];
    uint h0, h1, h2, h3, l0, l1, l2, l3;
    h0 = pack_hi_lo(x[0], x[1], l0);
    h1 = pack_hi_lo(x[2], x[3], l1);
    h2 = pack_hi_lo(x[4], x[5], l2);
    h3 = pack_hi_lo(x[6], x[7], l3);
    const size_t off = ((size_t)w * 256 + n) * 512 + kg;
    *(uint4*)(WT_hi + off) = make_uint4(h0, h1, h2, h3);
    *(uint4*)(WT_lo + off) = make_uint4(l0, l1, l2, l3);
}

// ---------------------------------------------------------------------------
// prep_v: VT_hi/lo[b][n][k] = split(value[b][k][n]) — LDS 64x64 transpose.
// grid (8 n-tiles, 16 k-tiles, 4 b), 256 threads. k-tiles beyond the pv
// K-bound are skipped (pv contributions there are exactly 0 anyway).
// ---------------------------------------------------------------------------
__global__ __launch_bounds__(256) void prep_v(
    const float* __restrict__ value, const int* __restrict__ vlen,
    ushort* __restrict__ VT_hi, ushort* __restrict__ VT_lo)
{
    __shared__ float t[64][69];
    const int b = blockIdx.z;
    const int k0 = blockIdx.y * 64, n0 = blockIdx.x * 64;
    const int kendB = (vlen[b] + 31) & ~31;
    if (k0 >= kendB) return;

    const int tid = threadIdx.x;
    const int n_in = (tid & 15) * 4, k_in = tid >> 4;
    const float* src = value + ((size_t)b * 1024 + k0 + k_in) * 512 + n0 + n_in;
    #pragma unroll
    for (int p = 0; p < 4; ++p) {
        const float4 x = *(const float4*)(src + (size_t)p * 16 * 512);
        t[k_in + p * 16][n_in + 0] = x.x;
        t[k_in + p * 16][n_in + 1] = x.y;
        t[k_in + p * 16][n_in + 2] = x.z;
        t[k_in + p * 16][n_in + 3] = x.w;
    }
    __syncthreads();

    const int rn = tid >> 2, c0 = (tid & 3) * 16;
    uint hp[8], lp[8];
    #pragma unroll
    for (int i = 0; i < 8; ++i)
        hp[i] = pack_hi_lo(t[c0 + 2 * i][rn], t[c0 + 2 * i + 1][rn], lp[i]);
    const size_t off = ((size_t)b * 512 + n0 + rn) * 1024 + k0 + c0;
    *(uint4*)(VT_hi + off) = make_uint4(hp[0], hp[1], hp[2], hp[3]);
    *(uint4*)(VT_hi + off + 8) = make_uint4(hp[4], hp[5], hp[6], hp[7]);
    *(uint4*)(VT_lo + off) = make_uint4(lp[0], lp[1], lp[2], lp[3]);
    *(uint4*)(VT_lo + off + 8) = make_uint4(lp[4], lp[5], lp[6], lp[7]);
}

// ---------------------------------------------------------------------------
// Kernel P (MFMA): proj via 3-MFMA hi/lo bf16 split. Wave tile 32m x 64n,
// K=512 by 32, register double-buffered.
// ---------------------------------------------------------------------------
#define LOADF(s, kbase) { const int ko = (kbase) + half * 8;                \
    _Pragma("unroll") for (int f = 0; f < 2; ++f) {                         \
        ah##s[f] = *(const short8v*)(a_h + (size_t)(f * 16) * 512 + ko);    \
        al##s[f] = *(const short8v*)(a_l + (size_t)(f * 16) * 512 + ko); }  \
    _Pragma("unroll") for (int f = 0; f < 4; ++f) {                         \
        bh##s[f] = *(const short8v*)(wt_h + (size_t)(f * 16) * 512 + ko);   \
        bl##s[f] = *(const short8v*)(wt_l + (size_t)(f * 16) * 512 + ko); } }

#define MFMAS(s)                                                                          \
    _Pragma("unroll") for (int mf = 0; mf < 2; ++mf)                                      \
    _Pragma("unroll") for (int nf = 0; nf < 4; ++nf) {                                    \
        acc[mf][nf] = __builtin_amdgcn_mfma_f32_16x16x32_bf16(ah##s[mf], bh##s[nf], acc[mf][nf], 0, 0, 0); \
        acc[mf][nf] = __builtin_amdgcn_mfma_f32_16x16x32_bf16(ah##s[mf], bl##s[nf], acc[mf][nf], 0, 0, 0); \
        acc[mf][nf] = __builtin_amdgcn_mfma_f32_16x16x32_bf16(al##s[mf], bh##s[nf], acc[mf][nf], 0, 0, 0); }

__global__ __launch_bounds__(64) void proj_mfma(
    const ushort* __restrict__ A_hi, const ushort* __restrict__ A_lo,
    const ushort* __restrict__ WT_hi, const ushort* __restrict__ WT_lo,
    const int* __restrict__ valid_len,
    float* __restrict__ EqT, float* __restrict__ EkT)
{
    const int lane = threadIdx.x;
    const int n0 = blockIdx.x * 64;
    const int m0 = blockIdx.y * 32;
    const bool isq = (m0 < 1024);
    int b = 0, kk0 = 0;
    if (!isq) {
        kk0 = (m0 - 1024) & 1023;
        b = (m0 - 1024) >> 10;
        if (kk0 >= valid_len[b]) return;
    }
    const int r = lane & 15, half = lane >> 4;
    const size_t wsel = isq ? 0 : (size_t)256 * 512;
    const ushort* wt_h = WT_hi + wsel + (size_t)(n0 + r) * 512;
    const ushort* wt_l = WT_lo + wsel + (size_t)(n0 + r) * 512;
    const ushort* a_h = A_hi + (size_t)(m0 + r) * 512;
    const ushort* a_l = A_lo + (size_t)(m0 + r) * 512;

    float4v acc[2][4] = {{{0.f}}};
    short8v ah0[2], al0[2], bh0[4], bl0[4];
    short8v ah1[2], al1[2], bh1[4], bl1[4];

    LOADF(0, 0);
    for (int kt = 0; kt < 512; kt += 64) {
        LOADF(1, kt + 32);
        MFMAS(0);
        if (kt + 64 < 512) LOADF(0, kt + 64);
        MFMAS(1);
    }

    #pragma unroll
    for (int mf = 0; mf < 2; ++mf) {
        #pragma unroll
        for (int nf = 0; nf < 4; ++nf) {
            float4v e;
            #pragma unroll
            for (int i = 0; i < 4; ++i)
                e[i] = __builtin_amdgcn_exp2f(acc[mf][nf][i] * TWO_LOG2E);
            if (isq) {
                *(float4v*)(EqT + (size_t)(n0 + nf * 16 + r) * 1024 +
                            m0 + mf * 16 + half * 4) = e;
            } else {
                *(float4v*)(EkT + (size_t)(b * 256 + n0 + nf * 16 + r) * 1024 +
                            kk0 + mf * 16 + half * 4) = e;
            }
        }
    }
}

// ---------------------------------------------------------------------------
// Kernel C: fused score + masked softmax, bf16 hi/lo attn output.
// softmax is shift-invariant, so score = -2*sum_h wv[h]*rcp(Eq*Ek+1)
// (the constant sum_h wv[h] cancels — no serial cw chain).
// block = (b, 4 q-rows); 512 threads; thread owns k = 2*tid, 2*tid+1.
// ---------------------------------------------------------------------------
__global__ __launch_bounds__(512) void score_softmax_kernel(
    const float* __restrict__ EqT, const float* __restrict__ EkT,
    const float* __restrict__ wv, const int* __restrict__ valid_len,
    ushort* __restrict__ attn_hi, ushort* __restrict__ attn_lo)
{
    __shared__ float wv_s[256];
    __shared__ float eq4_s[256 * 4];   // [h][q]
    __shared__ float red[8][4];

    const int tid = threadIdx.x;
    const int b = blockIdx.x >> 6;
    const int q0 = (blockIdx.x & 63) << 2;

    const int vlen = valid_len[b];
    const int k0 = tid * 2;
    const bool v0 = (k0 < vlen), v1 = (k0 + 1 < vlen);

    if (tid < 256) {
        wv_s[tid] = wv[tid];
        *(float4*)&eq4_s[tid * 4] =
            *(const float4*)(EqT + (size_t)tid * 1024 + b * 256 + q0);
    }
    __syncthreads();

    float acc[4][2] = {};

    if (v0) {   // whole waves with k0 >= vlen skip the h-loop entirely
        const float* ekp = EkT + (size_t)(b * 256) * 1024 + k0;
        #pragma unroll 4
        for (int h = 0; h < 256; ++h) {
            const float2 ek = *(const float2*)(ekp + (size_t)h * 1024);
            const float4 eq = *(const float4*)&eq4_s[h * 4];
            const float w = wv_s[h];
            acc[0][0] = fmaf(w, __builtin_amdgcn_rcpf(fmaf(eq.x, ek.x, 1.f)), acc[0][0]);
            acc[0][1] = fmaf(w, __builtin_amdgcn_rcpf(fmaf(eq.x, ek.y, 1.f)), acc[0][1]);
            acc[1][0] = fmaf(w, __builtin_amdgcn_rcpf(fmaf(eq.y, ek.x, 1.f)), acc[1][0]);
            acc[1][1] = fmaf(w, __builtin_amdgcn_rcpf(fmaf(eq.y, ek.y, 1.f)), acc[1][1]);
            acc[2][0] = fmaf(w, __builtin_amdgcn_rcpf(fmaf(eq.z, ek.x, 1.f)), acc[2][0]);
            acc[2][1] = fmaf(w, __builtin_amdgcn_rcpf(fmaf(eq.z, ek.y, 1.f)), acc[2][1]);
            acc[3][0] = fmaf(w, __builtin_amdgcn_rcpf(fmaf(eq.w, ek.x, 1.f)), acc[3][0]);
            acc[3][1] = fmaf(w, __builtin_amdgcn_rcpf(fmaf(eq.w, ek.y, 1.f)), acc[3][1]);
        }
    }

    float s[4][2], m[4];
    #pragma unroll
    for (int q = 0; q < 4; ++q) {
        s[q][0] = -2.f * acc[q][0];
        s[q][1] = -2.f * acc[q][1];
        float mm = -1e30f;
        if (v0) mm = s[q][0];
        if (v1) mm = fmaxf(mm, s[q][1]);
        m[q] = mm;
    }
    #pragma unroll
    for (int o = 32; o; o >>= 1) {
        #pragma unroll
        for (int q = 0; q < 4; ++q) m[q] = fmaxf(m[q], __shfl_xor(m[q], o));
    }
    const int wid = tid >> 6;
    if ((tid & 63) == 0) {
        #pragma unroll
        for (int q = 0; q < 4; ++q) red[wid][q] = m[q];
    }
    __syncthreads();
    #pragma unroll
    for (int q = 0; q < 4; ++q) {
        float mm = red[0][q];
        #pragma unroll
        for (int w = 1; w < 8; ++w) mm = fmaxf(mm, red[w][q]);
        m[q] = mm;
    }
    __syncthreads();

    float p[4][2], l[4];
    #pragma unroll
    for (int q = 0; q < 4; ++q) {
        p[q][0] = v0 ? __builtin_amdgcn_exp2f((s[q][0] - m[q]) * LOG2E) : 0.f;
        p[q][1] = v1 ? __builtin_amdgcn_exp2f((s[q][1] - m[q]) * LOG2E) : 0.f;
        l[q] = p[q][0] + p[q][1];
    }
    #pragma unroll
    for (int o = 32; o; o >>= 1) {
        #pragma unroll
        for (int q = 0; q < 4; ++q) l[q] += __shfl_xor(l[q], o);
    }
    if ((tid & 63) == 0) {
        #pragma unroll
        for (int q = 0; q < 4; ++q) red[wid][q] = l[q];
    }
    __syncthreads();
    #pragma unroll
    for (int q = 0; q < 4; ++q) {
        float ss = red[0][q];
        #pragma unroll
        for (int w = 1; w < 8; ++w) ss += red[w][q];
        const float rl = __builtin_amdgcn_rcpf(ss);
        const float a0 = p[q][0] * rl, a1 = p[q][1] * rl;
        uint lo;
        const uint hi = pack_hi_lo(a0, a1, lo);
        const size_t off = (size_t)(b * 256 + q0 + q) * 1024 + k0;
        *(uint*)(attn_hi + off) = hi;
        *(uint*)(attn_lo + off) = lo;
    }
}

// ---------------------------------------------------------------------------
// Kernel D (MFMA): out[b] = attn[b] @ value[b] via 3-MFMA hi/lo bf16.
// 1 wave per block, wave tile 16q x 32n, K bounded by ceil(vlen/32),
// register double-buffered. grid (16 n, 16 q, 4 b) = 1024 waves.
// ---------------------------------------------------------------------------
#define PVLOAD(s, ko) {                                   \
    ah##s = *(const short8v*)(ah_p + (ko));               \
    al##s = *(const short8v*)(al_p + (ko));               \
    bh0##s = *(const short8v*)(bh_p + (ko));              \
    bl0##s = *(const short8v*)(bl_p + (ko));              \
    bh1##s = *(const short8v*)(bh_p + 16 * 1024 + (ko));  \
    bl1##s = *(const short8v*)(bl_p + 16 * 1024 + (ko)); }

#define PVMFMA(s) {                                                              \
    acc0 = __builtin_amdgcn_mfma_f32_16x16x32_bf16(ah##s, bh0##s, acc0, 0, 0, 0); \
    acc0 = __builtin_amdgcn_mfma_f32_16x16x32_bf16(ah##s, bl0##s, acc0, 0, 0, 0); \
    acc0 = __builtin_amdgcn_mfma_f32_16x16x32_bf16(al##s, bh0##s, acc0, 0, 0, 0); \
    acc1 = __builtin_amdgcn_mfma_f32_16x16x32_bf16(ah##s, bh1##s, acc1, 0, 0, 0); \
    acc1 = __builtin_amdgcn_mfma_f32_16x16x32_bf16(ah##s, bl1##s, acc1, 0, 0, 0); \
    acc1 = __builtin_amdgcn_mfma_f32_16x16x32_bf16(al##s, bh1##s, acc1, 0, 0, 0); }

__global__ __launch_bounds__(64) void pv_mfma(
    const ushort* __restrict__ attn_hi, const ushort* __restrict__ attn_lo,
    const ushort* __restrict__ VT_hi, const ushort* __restrict__ VT_lo,
    const int* __restrict__ valid_len,
    float* __restrict__ out)
{
    const int lane = threadIdx.x;
    const int n0 = blockIdx.x * 32;
    const int q0 = blockIdx.y * 16;
    const int b = blockIdx.z;
    const int r = lane & 15, half = lane >> 4;
    const int kend = (valid_len[b] + 31) & ~31;

    const ushort* ah_p = attn_hi + (size_t)(b * 256 + q0 + r) * 1024 + half * 8;
    const ushort* al_p = attn_lo + (size_t)(b * 256 + q0 + r) * 1024 + half * 8;
    const ushort* bh_p = VT_hi + (size_t)(b * 512 + n0 + r) * 1024 + half * 8;
    const ushort* bl_p = VT_lo + (size_t)(b * 512 + n0 + r) * 1024 + half * 8;

    float4v acc0 = {0.f}, acc1 = {0.f};
    short8v ah0, al0, bh00, bl00, bh10, bl10;
    short8v ah1, al1, bh01, bl01, bh11, bl11;

    PVLOAD(0, 0);
    for (int kt = 0; kt < kend; kt += 64) {
        if (kt + 32 < kend) PVLOAD(1, kt + 32);
        PVMFMA(0);
        if (kt + 64 < kend) PVLOAD(0, kt + 64);
        if (kt + 32 < kend) PVMFMA(1);
    }

    float* op = out + (size_t)b * 256 * 512 + (size_t)(q0 + half * 4) * 512 + n0 + r;
    #pragma unroll
    for (int i = 0; i < 4; ++i) {
        op[(size_t)i * 512] = acc0[i];
        op[(size_t)i * 512 + 16] = acc1[i];
    }
}

// ---------------------------------------------------------------------------
extern "C" void kernel_launch(void* const* d_in, const int* in_sizes, int n_in,
                              void* d_out, int out_size, void* d_ws, size_t ws_size,
                              hipStream_t stream)
{
    const float* query = (const float*)d_in[0];   // [4,256,512]
    const float* key   = (const float*)d_in[1];   // [4,1024,512]
    const float* value = (const float*)d_in[2];   // [4,1024,512]
    const int*   vlen  = (const int*)d_in[3];     // [4]
    const float* Wq    = (const float*)d_in[4];   // [512,256]
    const float* Wk    = (const float*)d_in[5];   // [512,256]
    const float* wv    = (const float*)d_in[6];   // [256]
    float* out = (float*)d_out;                   // [4,256,512]

    float*  EqT     = (float*)d_ws;               // [256][1024]    = 262144 f
    float*  EkT     = EqT + 262144;               // [4][256][1024] = 1048576 f
    ushort* A_hi    = (ushort*)(EkT + 1048576);   // [5120][512]
    ushort* A_lo    = A_hi + 2621440;
    ushort* WT_hi   = A_lo + 2621440;             // [2][256][512]
    ushort* WT_lo   = WT_hi + 262144;
    ushort* attn_hi = WT_lo + 262144;             // [1024][1024]
    ushort* attn_lo = attn_hi + 1048576;
    ushort* VT_hi   = attn_lo + 1048576;          // [4][512][1024]
    ushort* VT_lo   = VT_hi + 2097152;

    hipLaunchKernelGGL(prep_w, dim3(128), dim3(256), 0, stream,
                       Wq, Wk, WT_hi, WT_lo);
    hipLaunchKernelGGL(prep_a, dim3(1280), dim3(256), 0, stream,
                       query, key, vlen, A_hi, A_lo);
    hipLaunchKernelGGL(prep_v, dim3(8, 16, 4), dim3(256), 0, stream,
                       value, vlen, VT_hi, VT_lo);
    hipLaunchKernelGGL(proj_mfma, dim3(4, 160), dim3(64), 0, stream,
                       A_hi, A_lo, WT_hi, WT_lo, vlen, EqT, EkT);
    hipLaunchKernelGGL(score_softmax_kernel, dim3(256), dim3(512), 0, stream,
                       EqT, EkT, wv, vlen, attn_hi, attn_lo);
    hipLaunchKernelGGL(pv_mfma, dim3(16, 16, 4), dim3(64), 0, stream,
                       attn_hi, attn_lo, VT_hi, VT_lo, vlen, out);
}